// Round 15
// baseline (2477.874 us; speedup 1.0000x reference)
//
#include <hip/hip_runtime.h>
#include <hip/hip_bf16.h>
#include <stdint.h>

#define B_ 32
#define C_ 768
#define NH_ 12
#define HD_ 64
#define NP_ 196
#define NTOK 197
#define NKEEP 98
#define NCLS_ 1000
#define MPAD 6400
#define RS_ (3 * C_)   // QKV row stride

typedef __bf16 bf16x8 __attribute__((ext_vector_type(8)));
typedef float f32x4 __attribute__((ext_vector_type(4)));

// ---------------- block reduction (256 threads) ----------------
__device__ __forceinline__ float blockReduceSum256(float v) {
    __shared__ float red[4];
    const int lane = threadIdx.x & 63, w = threadIdx.x >> 6;
#pragma unroll
    for (int off = 32; off; off >>= 1) v += __shfl_down(v, off);
    __syncthreads();
    if (lane == 0) red[w] = v;
    __syncthreads();
    return red[0] + red[1] + red[2] + red[3];
}

// ---------------- async global->LDS (16B per lane) ----------------
__device__ __forceinline__ void gload16(void* lds, const void* g) {
    __builtin_amdgcn_global_load_lds(
        (const __attribute__((address_space(1))) void*)g,
        (__attribute__((address_space(3))) void*)lds,
        16, 0, 0);
}

// ---------------- patchify: (B,3,224,224) -> bf16 (B*196, 768) ----------------
__global__ __launch_bounds__(256) void patchify_kernel(const float* __restrict__ img,
                                                       __hip_bfloat16* __restrict__ patches)
{
    const int bp = blockIdx.x;
    const int b = bp / NP_, p = bp % NP_;
    const int gy = p / 14, gx = p % 14;
    const int tid = threadIdx.x;
#pragma unroll
    for (int j = 0; j < 3; ++j) {
        const int e = tid + j * 256;
        const int c = e >> 8, rem = e & 255, py = rem >> 4, px = rem & 15;
        patches[(size_t)bp * C_ + e] = __float2bfloat16(
            img[(((size_t)b * 3 + c) * 224 + gy * 16 + py) * 224 + gx * 16 + px]);
    }
}

// ---------------- x = concat(cls, pemb) + pos ----------------
__global__ __launch_bounds__(256) void assemble_x_kernel(const float* __restrict__ pemb,
                                                         const float* __restrict__ cls_tok,
                                                         const float* __restrict__ pos,
                                                         float* __restrict__ x)
{
    const int b = blockIdx.x, t = blockIdx.y, tid = threadIdx.x;
#pragma unroll
    for (int j = 0; j < 3; ++j) {
        const int c = tid + j * 256;
        const float v = (t == 0) ? cls_tok[c] : pemb[((size_t)b * NP_ + (t - 1)) * C_ + c];
        x[((size_t)b * NTOK + t) * C_ + c] = v + pos[(size_t)t * C_ + c];
    }
}

// ---------------- layernorm: wave per row ----------------
__global__ __launch_bounds__(256) void ln_kernel(const float* __restrict__ x,
                                                 const float* __restrict__ g,
                                                 const float* __restrict__ b,
                                                 __hip_bfloat16* outB, float* outF,
                                                 long long inRowStride, int nRows)
{
    const int row = (blockIdx.x << 2) + (threadIdx.x >> 6);
    const int lane = threadIdx.x & 63;
    if (row >= nRows) return;
    const float* xr = x + (size_t)row * inRowStride;
    float4 v0 = *(const float4*)(xr + (lane << 2));
    float4 v1 = *(const float4*)(xr + 256 + (lane << 2));
    float4 v2 = *(const float4*)(xr + 512 + (lane << 2));
    float s = v0.x + v0.y + v0.z + v0.w + v1.x + v1.y + v1.z + v1.w
            + v2.x + v2.y + v2.z + v2.w;
#pragma unroll
    for (int off = 1; off < 64; off <<= 1) s += __shfl_xor(s, off);
    const float mu = s * (1.f / C_);
    float q = 0.f;
    {
        float d;
        d = v0.x - mu; q += d * d; d = v0.y - mu; q += d * d;
        d = v0.z - mu; q += d * d; d = v0.w - mu; q += d * d;
        d = v1.x - mu; q += d * d; d = v1.y - mu; q += d * d;
        d = v1.z - mu; q += d * d; d = v1.w - mu; q += d * d;
        d = v2.x - mu; q += d * d; d = v2.y - mu; q += d * d;
        d = v2.z - mu; q += d * d; d = v2.w - mu; q += d * d;
    }
#pragma unroll
    for (int off = 1; off < 64; off <<= 1) q += __shfl_xor(q, off);
    const float rs = rsqrtf(q * (1.f / C_) + 1e-6f);
    const float4 vv[3] = {v0, v1, v2};
#pragma unroll
    for (int j = 0; j < 3; ++j) {
        const int cbase = (j << 8) + (lane << 2);
        const float4 gv = *(const float4*)(g + cbase);
        const float4 bv = *(const float4*)(b + cbase);
        float o0 = (vv[j].x - mu) * rs * gv.x + bv.x;
        float o1 = (vv[j].y - mu) * rs * gv.y + bv.y;
        float o2 = (vv[j].z - mu) * rs * gv.z + bv.z;
        float o3 = (vv[j].w - mu) * rs * gv.w + bv.w;
        if (outB) {
            union { unsigned short us[4]; uint2 u; } pk;
            __hip_bfloat16 h;
            h = __float2bfloat16(o0); pk.us[0] = *(unsigned short*)&h;
            h = __float2bfloat16(o1); pk.us[1] = *(unsigned short*)&h;
            h = __float2bfloat16(o2); pk.us[2] = *(unsigned short*)&h;
            h = __float2bfloat16(o3); pk.us[3] = *(unsigned short*)&h;
            *(uint2*)((unsigned short*)outB + (size_t)row * C_ + cbase) = pk.u;
        }
        if (outF) {
            float4 o; o.x = o0; o.y = o1; o.z = o2; o.w = o3;
            *(float4*)(outF + (size_t)row * C_ + cbase) = o;
        }
    }
}

// ---------------- weight transpose+convert: fp32 [K][N] -> bf16 [N][K] ----------------
__global__ __launch_bounds__(256) void transpose_bf16_kernel(const float* __restrict__ W,
                                                             __hip_bfloat16* __restrict__ Wt,
                                                             int K, int N,
                                                             long long outLstride, long long outOff)
{
    __shared__ float tile[32][33];
    const size_t loffIn = (size_t)blockIdx.z * K * N;
    const size_t loffOut = (size_t)blockIdx.z * outLstride + outOff;
    const int k0 = blockIdx.y << 5, n0 = blockIdx.x << 5;
    const int tid = threadIdx.x;
#pragma unroll
    for (int e = tid; e < 1024; e += 256) {
        const int r = e >> 5, c = e & 31;
        tile[r][c] = W[loffIn + (size_t)(k0 + r) * N + n0 + c];
    }
    __syncthreads();
#pragma unroll
    for (int e = tid; e < 1024; e += 256) {
        const int r = e >> 5, c = e & 31;
        Wt[loffOut + (size_t)(n0 + r) * K + k0 + c] = __float2bfloat16(tile[c][r]);
    }
}

// ---------------- concat qk_b / v_b into per-layer 2304 bias ----------------
__global__ __launch_bounds__(256) void concat_bias_kernel(const float* __restrict__ qk_b,
                                                          const float* __restrict__ v_b,
                                                          float* __restrict__ out)
{
    const int i = blockIdx.x * 256 + threadIdx.x;
    if (i < 12 * RS_) {
        const int l = i / RS_, c = i % RS_;
        out[i] = (c < 2 * C_) ? qk_b[l * 2 * C_ + c] : v_b[l * C_ + (c - 2 * C_)];
    }
}

// ---------------- bf16 MFMA GEMM: 128x128 tile, BK=32, double-buffered, 32KB LDS ----------------
// (round-10 proven: pair-line layout, counted vmcnt(4), launch_bounds(256,4))
template<int GELU, int OMODE>
__global__ __launch_bounds__(256, 4) void gemm_bf16_kernel(const __hip_bfloat16* __restrict__ A,
                                                           const __hip_bfloat16* __restrict__ Bt,
                                                           const float* __restrict__ bias,
                                                           const float* __restrict__ res,
                                                           float* __restrict__ outF,
                                                           __hip_bfloat16* __restrict__ outB,
                                                           int K, int N)
{
    __shared__ __align__(16) unsigned short sMem[16384];  // 32KB
    const int tid = threadIdx.x;
    const int wv = tid >> 6, ln = tid & 63;

    const int nwg = gridDim.x * gridDim.y;
    int lid = blockIdx.y * gridDim.x + blockIdx.x;
    {
        const int q = nwg >> 3, r = nwg & 7;
        const int xcd = lid & 7, lq = lid >> 3;
        lid = (xcd < r ? xcd * (q + 1) : r * (q + 1) + (xcd - r) * q) + lq;
    }
    const int bn = (lid % gridDim.x) << 7;
    const int bm = (lid / gridDim.x) << 7;

    const int wr = wv >> 1, wc = wv & 1;
    const int ln15 = ln & 15, lhi = ln >> 4;

    int offA[2], offB[2];
#pragma unroll
    for (int i = 0; i < 2; ++i) {
        const int s = (i << 8) + tid;
        const int L = s >> 3, cp = (s & 7) ^ (L & 7);
        offA[i] = (bm + (L << 1) + (cp >> 2)) * K + ((cp & 3) << 3);
        offB[i] = (bn + (L << 1) + (cp >> 2)) * K + ((cp & 3) << 3);
    }

    const unsigned ldsBase =
        (unsigned)(size_t)(__attribute__((address_space(3))) unsigned short*)&sMem[0];
    unsigned aOff[4], bOff[4];
#pragma unroll
    for (int m = 0; m < 4; ++m) {
        const int r = (wr << 6) + (m << 4) + ln15;
        const int L = r >> 1;
        const int pc = (((r & 1) << 2) + lhi) ^ (L & 7);
        aOff[m] = (unsigned)((L << 7) + (pc << 4));
    }
#pragma unroll
    for (int n = 0; n < 4; ++n) {
        const int r = (wc << 6) + (n << 4) + ln15;
        const int L = r >> 1;
        const int pc = (((r & 1) << 2) + lhi) ^ (L & 7);
        bOff[n] = (unsigned)(8192 + (L << 7) + (pc << 4));
    }

    f32x4 acc[4][4] = {};

    auto stage = [&](int bufByte, int kt) {
        const int k0 = kt << 5;
        unsigned short* base = sMem + (bufByte >> 1);
        gload16(base + ((0 * 256 + (wv << 6)) << 3), A + offA[0] + k0);
        gload16(base + ((1 * 256 + (wv << 6)) << 3), A + offA[1] + k0);
        gload16(base + 4096 + ((0 * 256 + (wv << 6)) << 3), Bt + offB[0] + k0);
        gload16(base + 4096 + ((1 * 256 + (wv << 6)) << 3), Bt + offB[1] + k0);
    };
    auto compute = [&](unsigned bufOff) {
        bf16x8 a[4], b[4];
#pragma unroll
        for (int m = 0; m < 4; ++m)
            asm volatile("ds_read_b128 %0, %1" : "=v"(a[m]) : "v"(ldsBase + bufOff + aOff[m]));
#pragma unroll
        for (int n = 0; n < 4; ++n)
            asm volatile("ds_read_b128 %0, %1" : "=v"(b[n]) : "v"(ldsBase + bufOff + bOff[n]));
        asm volatile("s_waitcnt lgkmcnt(0)" ::: "memory");
        __builtin_amdgcn_sched_barrier(0);
#pragma unroll
        for (int m = 0; m < 4; ++m)
#pragma unroll
            for (int n = 0; n < 4; ++n)
                acc[m][n] = __builtin_amdgcn_mfma_f32_16x16x32_bf16(a[m], b[n], acc[m][n], 0, 0, 0);
    };

    const int ntiles = K >> 5;
    stage(0, 0);
    asm volatile("s_waitcnt vmcnt(0)" ::: "memory");
    __builtin_amdgcn_s_barrier();
    int t = 0;
    for (; t + 2 < ntiles; t += 2) {
        stage(16384, t + 1);
        asm volatile("s_waitcnt vmcnt(4)" ::: "memory");
        __builtin_amdgcn_s_barrier();
        compute(0u);
        __builtin_amdgcn_s_barrier();
        stage(0, t + 2);
        asm volatile("s_waitcnt vmcnt(4)" ::: "memory");
        __builtin_amdgcn_s_barrier();
        compute(16384u);
        __builtin_amdgcn_s_barrier();
    }
    stage(16384, ntiles - 1);
    asm volatile("s_waitcnt vmcnt(4)" ::: "memory");
    __builtin_amdgcn_s_barrier();
    compute(0u);
    __builtin_amdgcn_s_barrier();
    asm volatile("s_waitcnt vmcnt(0)" ::: "memory");
    __builtin_amdgcn_s_barrier();
    compute(16384u);
    __syncthreads();

    if (OMODE == 0) {
        unsigned short* sOut = sMem;
#pragma unroll
        for (int n = 0; n < 4; ++n) {
            const int col = (wc << 6) + (n << 4) + ln15;
            const float bv = bias[bn + col];
#pragma unroll
            for (int m = 0; m < 4; ++m) {
                const int row0 = (wr << 6) + (m << 4) + (lhi << 2);
#pragma unroll
                for (int r = 0; r < 4; ++r) {
                    float x = acc[m][n][r] + bv;
                    if (GELU) x = 0.5f * x * (1.f + erff(x * 0.70710678118654752f));
                    const __hip_bfloat16 hb = __float2bfloat16(x);
                    sOut[(row0 + r) * 128 + col] = *(const unsigned short*)&hb;
                }
            }
        }
        __syncthreads();
#pragma unroll
        for (int i = 0; i < 8; ++i) {
            const int chunk = (i << 8) + tid;
            const int row = chunk >> 4, c8 = (chunk & 15) << 3;
            *(uint4*)((unsigned short*)outB + (size_t)(bm + row) * N + bn + c8) =
                *(const uint4*)(sOut + row * 128 + c8);
        }
    } else {
#pragma unroll
        for (int n = 0; n < 4; ++n) {
            const int gcn = bn + (wc << 6) + (n << 4) + ln15;
            const float bv = bias[gcn];
#pragma unroll
            for (int m = 0; m < 4; ++m) {
                const int gr0 = bm + (wr << 6) + (m << 4) + (lhi << 2);
                f32x4 v = acc[m][n];
#pragma unroll
                for (int r = 0; r < 4; ++r) {
                    const size_t o = (size_t)(gr0 + r) * N + gcn;
                    float x = v[r] + bv;
                    if (OMODE == 1) x += res[o];
                    outF[o] = x;
                }
            }
        }
    }
}

// ---------------- HALF bf16 MFMA GEMM: 64x128 tile, BK=32, 4-stage REGISTER-PREFETCH ----------------
// OMODE 1: f32 + res; 2: f32; 3: SPLIT-K PARTIAL (no bias/res; blockIdx.z selects
// K-slice; writes fp32 partial to outF + z*pstride). ksplit=1 for OMODE 1/2.
#define HSTEP(VMC, PBUF, SBUF, CA, CB, NA, NB, DOSTAGE, DOPRE, KS)             \
    {                                                                          \
        asm volatile("s_waitcnt vmcnt(" VMC ")" ::: "memory");                 \
        __builtin_amdgcn_s_barrier();                                          \
        if (DOSTAGE) stage((SBUF) * 6144, (KS));                               \
        if (DOPRE) {                                                           \
            _Pragma("unroll")                                                  \
            for (int m_ = 0; m_ < 2; ++m_)                                     \
                asm volatile("ds_read_b128 %0, %1"                             \
                    : "=v"(NA[m_]) : "v"(ldsBase + (PBUF) * 12288u + aOff[m_]));\
            _Pragma("unroll")                                                  \
            for (int n_ = 0; n_ < 4; ++n_)                                     \
                asm volatile("ds_read_b128 %0, %1"                             \
                    : "=v"(NB[n_]) : "v"(ldsBase + (PBUF) * 12288u + bOff[n_]));\
            asm volatile("s_waitcnt lgkmcnt(6)" ::: "memory");                 \
        } else {                                                               \
            asm volatile("s_waitcnt lgkmcnt(0)" ::: "memory");                 \
        }                                                                      \
        __builtin_amdgcn_sched_barrier(0);                                     \
        _Pragma("unroll")                                                      \
        for (int m_ = 0; m_ < 2; ++m_)                                         \
            _Pragma("unroll")                                                  \
            for (int n_ = 0; n_ < 4; ++n_)                                     \
                acc[m_][n_] = __builtin_amdgcn_mfma_f32_16x16x32_bf16(         \
                    CA[m_], CB[n_], acc[m_][n_], 0, 0, 0);                     \
    }

template<int OMODE>
__global__ __launch_bounds__(256, 4) void gemm_half_kernel(const __hip_bfloat16* __restrict__ A,
                                                           const __hip_bfloat16* __restrict__ Bt,
                                                           const float* __restrict__ bias,
                                                           const float* __restrict__ res,
                                                           float* __restrict__ outF,
                                                           int K, int N,
                                                           int ksplit, size_t pstride)
{
    __shared__ __align__(16) unsigned short sMem[4 * 6144];  // 48KB: {A 4KB, B 8KB} x 4
    const int tid = threadIdx.x;
    const int wv = tid >> 6, ln = tid & 63;

    const int nwg = gridDim.x * gridDim.y;
    int lid = blockIdx.y * gridDim.x + blockIdx.x;
    {
        const int q = nwg >> 3, r = nwg & 7;
        const int xcd = lid & 7, lq = lid >> 3;
        lid = (xcd < r ? xcd * (q + 1) : r * (q + 1) + (xcd - r) * q) + lq;
    }
    const int bn = (lid % gridDim.x) << 7;
    const int bm = (lid / gridDim.x) << 6;

    const int kloc = K / ksplit;                  // local K extent
    const int tb0 = ((int)blockIdx.z * kloc) >> 5; // absolute first tile

    const int wr = wv >> 1, wc = wv & 1;          // wave tile rows wr*32, cols wc*64
    const int ln15 = ln & 15, lhi = ln >> 4;

    int offA, offB[2];
    {
        const int L = tid >> 3, cp = (tid & 7) ^ (L & 7);
        offA = (bm + (L << 1) + (cp >> 2)) * K + ((cp & 3) << 3);
    }
#pragma unroll
    for (int i = 0; i < 2; ++i) {
        const int s = (i << 8) + tid;
        const int L = s >> 3, cp = (s & 7) ^ (L & 7);
        offB[i] = (bn + (L << 1) + (cp >> 2)) * K + ((cp & 3) << 3);
    }

    const unsigned ldsBase =
        (unsigned)(size_t)(__attribute__((address_space(3))) unsigned short*)&sMem[0];
    unsigned aOff[2], bOff[4];
#pragma unroll
    for (int m = 0; m < 2; ++m) {
        const int r = (wr << 5) + (m << 4) + ln15;
        const int L = r >> 1;
        const int pc = (((r & 1) << 2) + lhi) ^ (L & 7);
        aOff[m] = (unsigned)((L << 7) + (pc << 4));
    }
#pragma unroll
    for (int n = 0; n < 4; ++n) {
        const int r = (wc << 6) + (n << 4) + ln15;
        const int L = r >> 1;
        const int pc = (((r & 1) << 2) + lhi) ^ (L & 7);
        bOff[n] = (unsigned)(4096 + (L << 7) + (pc << 4));   // B at byte 4096 within buf
    }

    f32x4 acc[2][4] = {};
    bf16x8 r0a[2], r0b[4], r1a[2], r1b[4];

    auto stage = [&](int bufUShort, int kt) {
        const int k0 = (tb0 + kt) << 5;
        unsigned short* base = sMem + bufUShort;
        gload16(base + ((wv << 6) << 3), A + offA + k0);
        gload16(base + 2048 + ((0 * 256 + (wv << 6)) << 3), Bt + offB[0] + k0);
        gload16(base + 2048 + ((1 * 256 + (wv << 6)) << 3), Bt + offB[1] + k0);
    };

    const int ntiles = kloc >> 5;   // 24, 48, or 12 (divisible by 4, >= 8)
    stage(0, 0);
    stage(6144, 1);
    stage(12288, 2);
    asm volatile("s_waitcnt vmcnt(6)" ::: "memory");   // tile 0 landed
    __builtin_amdgcn_s_barrier();
#pragma unroll
    for (int m = 0; m < 2; ++m)
        asm volatile("ds_read_b128 %0, %1" : "=v"(r0a[m]) : "v"(ldsBase + aOff[m]));
#pragma unroll
    for (int n = 0; n < 4; ++n)
        asm volatile("ds_read_b128 %0, %1" : "=v"(r0b[n]) : "v"(ldsBase + bOff[n]));

    int t = 0;
    for (; t < ntiles - 4; t += 4) {
        HSTEP("3", 1, 3, r0a, r0b, r1a, r1b, true, true, t + 3);
        HSTEP("3", 2, 0, r1a, r1b, r0a, r0b, true, true, t + 4);
        HSTEP("3", 3, 1, r0a, r0b, r1a, r1b, true, true, t + 5);
        HSTEP("3", 0, 2, r1a, r1b, r0a, r0b, true, true, t + 6);
    }
    // tail: t == ntiles-4 (buffer phase 0, cur reg r0)
    HSTEP("3", 1, 3, r0a, r0b, r1a, r1b, true,  true,  t + 3);   // stages tile nt-1
    HSTEP("3", 2, 0, r1a, r1b, r0a, r0b, false, true,  0);
    HSTEP("0", 3, 0, r0a, r0b, r1a, r1b, false, true,  0);
    HSTEP("0", 0, 0, r1a, r1b, r0a, r0b, false, false, 0);

    float* outP = (OMODE == 3) ? (outF + (size_t)blockIdx.z * pstride) : outF;
#pragma unroll
    for (int n = 0; n < 4; ++n) {
        const int gcn = bn + (wc << 6) + (n << 4) + ln15;
        const float bv = (OMODE == 3) ? 0.f : bias[gcn];
#pragma unroll
        for (int m = 0; m < 2; ++m) {
            const int gr0 = bm + (wr << 5) + (m << 4) + (lhi << 2);
            f32x4 v = acc[m][n];
#pragma unroll
            for (int r = 0; r < 4; ++r) {
                const size_t o = (size_t)(gr0 + r) * N + gcn;
                float x = v[r] + bv;
                if (OMODE == 1) x += res[o];
                outP[o] = x;
            }
        }
    }
}

// ---------------- split-K combine: out = P0 + P1 + bias (+res), fixed order ----------------
template<int HASRES>
__global__ __launch_bounds__(256) void combine_kernel(const float* __restrict__ P,
                                                      size_t pstride,
                                                      const float* __restrict__ bias,
                                                      const float* __restrict__ res,
                                                      float* __restrict__ out,
                                                      int total, int N)
{
    const int idx = (blockIdx.x * 256 + threadIdx.x) << 2;
    if (idx >= total) return;
    const int c = idx % N;
    const float4 p0 = *(const float4*)(P + idx);
    const float4 p1 = *(const float4*)(P + pstride + idx);
    const float4 bv = *(const float4*)(bias + c);
    float4 o;
    o.x = p0.x + p1.x + bv.x;
    o.y = p0.y + p1.y + bv.y;
    o.z = p0.z + p1.z + bv.z;
    o.w = p0.w + p1.w + bv.w;
    if (HASRES) {
        const float4 r = *(const float4*)(res + idx);
        o.x += r.x; o.y += r.y; o.z += r.z; o.w += r.w;
    }
    *(float4*)(out + idx) = o;
}

// ---------------- head: out[m][n] = A[m] . W[:,n] + bias (fp32 exact) ----------------
__global__ __launch_bounds__(256) void head_kernel(const float* __restrict__ A,
                                                   const float* __restrict__ W,
                                                   const float* __restrict__ bias,
                                                   float* __restrict__ out)
{
    const int n = blockIdx.x * 256 + threadIdx.x;
    const int m = blockIdx.y;
    if (n >= NCLS_) return;
    const float* a = A + (size_t)m * C_;
    float s = 0.f;
#pragma unroll 8
    for (int k = 0; k < C_; ++k) s = fmaf(a[k], W[(size_t)k * NCLS_ + n], s);
    out[(size_t)m * NCLS_ + n] = s + bias[n];
}

// ---------------- MFMA attention (QKV fused input, row stride 3C) ----------------
template<int NT16>
__global__ __launch_bounds__(256) void attn_mfma_kernel(const __hip_bfloat16* __restrict__ qkv,
                                                        __hip_bfloat16* __restrict__ o,
                                                        float* __restrict__ attn0,
                                                        int Nt)
{
    constexpr int NPAD = NT16 * 16;
    constexpr int PSW = (((NPAD / 8) & 7) == 0) ? 7 : 3;
    constexpr int VSW = 7;
    constexpr int PROWB = NPAD * 2 + 16;
    constexpr int VROWB = (NPAD == 224) ? 528 : 272;
    __shared__ unsigned short sK[NPAD * 64 + 512];
    __shared__ unsigned short sV[32 * VROWB];

    const int bh = blockIdx.x;
    const int b = bh / NH_, h = bh % NH_;
    const int qtile = blockIdx.y;
    const int tid = threadIdx.x, ln = tid & 63, wv = tid >> 6;
    const int ln15 = ln & 15, lhi = ln >> 4;
    const __hip_bfloat16* qkbase = qkv + (size_t)b * Nt * RS_;

#pragma unroll
    for (int it = 0; it < NPAD * 8 / 256; ++it) {
        const int p = it * 256 + tid;
        int key = p >> 3;
        const int c = (p & 7) ^ (key & 7);
        if (key >= Nt) key = Nt - 1;
        unsigned short* dst = sK + (size_t)(it * 256 + (wv << 6)) * 8;
        gload16(dst, qkbase + (size_t)key * RS_ + C_ + (h << 6) + (c << 3));
    }
#pragma unroll
    for (int it = 0; it < NPAD * 8 / 256; ++it) {
        const int e = it * 256 + tid;
        const int key = e >> 3, dc = e & 7;
        union { uint4 u; unsigned short us[8]; } val;
        val.u = make_uint4(0u, 0u, 0u, 0u);
        if (key < Nt)
            val.u = *(const uint4*)(qkbase + (size_t)key * RS_ + 2 * C_ + (h << 6) + (dc << 3));
        const int kc = key >> 3, kb = (key & 7) << 1;
#pragma unroll
        for (int j = 0; j < 8; ++j) {
            const int d = (dc << 3) + j;
            *(unsigned short*)((char*)sV + d * VROWB + ((kc ^ ((d >> 3) & VSW)) << 4) + kb) = val.us[j];
        }
    }
    const int qbase = qtile * 64 + (wv << 4);
    int qrow = qbase + ln15; if (qrow >= Nt) qrow = Nt - 1;
    const __hip_bfloat16* qp = qkbase + (size_t)qrow * RS_ + (h << 6) + (lhi << 3);
    const bf16x8 qf0 = *(const bf16x8*)qp;
    const bf16x8 qf1 = *(const bf16x8*)(qp + 32);
    __syncthreads();

    f32x4 sc[NT16];
#pragma unroll
    for (int t = 0; t < NT16; ++t) {
        const int key = (t << 4) + ln15;
        const unsigned short* kr = sK + (size_t)key * 64;
        const bf16x8 k0 = *(const bf16x8*)(kr + ((lhi ^ (key & 7)) << 3));
        const bf16x8 k1 = *(const bf16x8*)(kr + (((4 + lhi) ^ (key & 7)) << 3));
        f32x4 a = {0.f, 0.f, 0.f, 0.f};
        a = __builtin_amdgcn_mfma_f32_16x16x32_bf16(k0, qf0, a, 0, 0, 0);
        a = __builtin_amdgcn_mfma_f32_16x16x32_bf16(k1, qf1, a, 0, 0, 0);
        sc[t] = a;
    }
    __syncthreads();

    float mx = -1e30f;
#pragma unroll
    for (int t = 0; t < NT16; ++t)
#pragma unroll
        for (int r = 0; r < 4; ++r) {
            const int key = (t << 4) + (lhi << 2) + r;
            const float v = (key < Nt) ? sc[t][r] * 0.125f : -1e30f;
            sc[t][r] = v;
            mx = fmaxf(mx, v);
        }
    mx = fmaxf(mx, __shfl_xor(mx, 16));
    mx = fmaxf(mx, __shfl_xor(mx, 32));
    float sum = 0.f;
#pragma unroll
    for (int t = 0; t < NT16; ++t)
#pragma unroll
        for (int r = 0; r < 4; ++r) {
            const float e = expf(sc[t][r] - mx);
            sc[t][r] = e; sum += e;
        }
    sum += __shfl_xor(sum, 16);
    sum += __shfl_xor(sum, 32);
    const float inv = 1.f / sum;

    char* Pw = (char*)sK + wv * (16 * PROWB);
    const bool isQ0 = (qtile == 0) && (wv == 0) && (ln15 == 0);
#pragma unroll
    for (int t = 0; t < NT16; ++t) {
        union { unsigned short us[4]; uint2 u2; } pk;
#pragma unroll
        for (int r = 0; r < 4; ++r) {
            const float p = sc[t][r] * inv;
            const __hip_bfloat16 hb = __float2bfloat16(p);
            pk.us[r] = *(const unsigned short*)&hb;
            if (isQ0) {
                const int key = (t << 4) + (lhi << 2) + r;
                if (key < Nt) attn0[(size_t)bh * NTOK + key] = p;
            }
        }
        const int chunk = ((t << 1) + (lhi >> 1)) ^ (ln15 & PSW);
        *(uint2*)(Pw + ln15 * PROWB + (chunk << 4) + ((lhi & 1) << 3)) = pk.u2;
    }
    __syncthreads();

    f32x4 oa[4] = {};
#pragma unroll
    for (int s = 0; s < NPAD / 32; ++s) {
        const bf16x8 pf = *(const bf16x8*)(Pw + ln15 * PROWB +
                                           ((((s << 2) + lhi) ^ (ln15 & PSW)) << 4));
#pragma unroll
        for (int n = 0; n < 4; ++n) {
            const int d = (n << 4) + ln15;
            const bf16x8 vf = *(const bf16x8*)((char*)sV + d * VROWB +
                                               ((((s << 2) + lhi) ^ ((d >> 3) & VSW)) << 4));
            oa[n] = __builtin_amdgcn_mfma_f32_16x16x32_bf16(pf, vf, oa[n], 0, 0, 0);
        }
    }
#pragma unroll
    for (int n = 0; n < 4; ++n)
#pragma unroll
        for (int r = 0; r < 4; ++r) {
            const int qq = qbase + (lhi << 2) + r;
            if (qq < Nt)
                o[((size_t)b * Nt + qq) * C_ + (h << 6) + (n << 4) + ln15] =
                    __float2bfloat16(oa[n][r]);
        }
}

// ---------------- row + cls EMA (full layers) ----------------
__global__ __launch_bounds__(256) void row_cls_ema_kernel(const float* __restrict__ attn0,
                                                          float* __restrict__ cls, int first)
{
    const int b = blockIdx.x, t = threadIdx.x;
    if (t < NP_) {
        float s = 0.f;
#pragma unroll
        for (int h = 0; h < NH_; ++h) s += attn0[((size_t)(b * NH_ + h)) * NTOK + 1 + t];
        const int i = b * NP_ + t;
        cls[i] = first ? s : 0.5f * cls[i] + 0.5f * s;
    }
}

// ---------------- row + cls update (pruned layers) ----------------
__global__ __launch_bounds__(256) void row_cls_prune_kernel(const float* __restrict__ attn0,
                                                            const float* __restrict__ sorted,
                                                            float* __restrict__ cls)
{
    const int b = blockIdx.x, t = threadIdx.x;
    if (t < NP_) {
        float sv = sorted[b * NP_ + t];
        if (t < NKEEP) {
            float s = 0.f;
#pragma unroll
            for (int h = 0; h < NH_; ++h) s += attn0[((size_t)(b * NH_ + h)) * NTOK + 1 + t];
            sv = 0.5f * sv + 0.5f * s;
        }
        cls[b * NP_ + t] = sv;
    }
}

// ---------------- stable descending rank-sort ----------------
__global__ __launch_bounds__(256) void rank_kernel(const float* __restrict__ cls,
                                                   int* __restrict__ idx,
                                                   float* __restrict__ sorted,
                                                   float* __restrict__ ssum)
{
    __shared__ float sv[NP_];
    const int b = blockIdx.x, t = threadIdx.x;
    if (t < NP_) sv[t] = cls[b * NP_ + t];
    __syncthreads();
    float val = 0.f; int r = NP_;
    if (t < NP_) {
        val = sv[t];
        r = 0;
        for (int j = 0; j < NP_; ++j) {
            const float vj = sv[j];
            r += (vj > val || (vj == val && j < t)) ? 1 : 0;
        }
        idx[b * NP_ + r] = t;
        sorted[b * NP_ + r] = val;
    }
    const float contrib = (t < NP_ && r >= NKEEP) ? val : 0.f;
    const float tot = blockReduceSum256(contrib);
    if (t == 0) ssum[b] = tot;
}

// ---------------- build xs / fast / rep, with FUSED LN1 -> Tb ----------------
__global__ __launch_bounds__(256) void build_xs_kernel(const float* __restrict__ x,
                                                       const int* __restrict__ idx,
                                                       const float* __restrict__ sorted,
                                                       const float* __restrict__ ssum,
                                                       float* __restrict__ xs,
                                                       float* __restrict__ fast,
                                                       float* __restrict__ rep,
                                                       const float* __restrict__ lng,
                                                       const float* __restrict__ lnb,
                                                       __hip_bfloat16* __restrict__ tb)
{
    const int b = blockIdx.x, t = blockIdx.y, tid = threadIdx.x;
    const float* xb = x + (size_t)b * NTOK * C_;

    float v0, v1, v2;
    int ldsRow = -1;

    if (t == 0) {
        v0 = xb[tid]; v1 = xb[tid + 256]; v2 = xb[tid + 512];
        ldsRow = 0;
    } else if (t <= NKEEP) {
        const int src = 1 + idx[b * NP_ + (t - 1)];
        const float* xr = xb + (size_t)src * C_;
        v0 = xr[tid]; v1 = xr[tid + 256]; v2 = xr[tid + 512];
        ldsRow = t;
    } else if (t == NKEEP + 1) {
        const float inv = 1.f / ssum[b];
        float a0 = 0.f, a1 = 0.f, a2 = 0.f;
        for (int jj = 0; jj < NP_ - NKEEP; ++jj) {
            const int src = 1 + idx[b * NP_ + NKEEP + jj];
            const float wgt = sorted[b * NP_ + NKEEP + jj];
            const float* xr = xb + (size_t)src * C_;
            a0 = fmaf(xr[tid], wgt, a0);
            a1 = fmaf(xr[tid + 256], wgt, a1);
            a2 = fmaf(xr[tid + 512], wgt, a2);
        }
        v0 = a0 * inv; v1 = a1 * inv; v2 = a2 * inv;
        rep[(size_t)b * C_ + tid] = v0;
        rep[(size_t)b * C_ + tid + 256] = v1;
        rep[(size_t)b * C_ + tid + 512] = v2;
        ldsRow = 99;
    } else {
        const int jf = t - (NKEEP + 2);
        const int src = 1 + idx[b * NP_ + NKEEP + jf];
#pragma unroll
        for (int j = 0; j < 3; ++j) {
            const int c = tid + j * 256;
            fast[((size_t)b * (NP_ - NKEEP) + jf) * C_ + c] = xb[(size_t)src * C_ + c];
        }
        return;
    }

    float* xsr = xs + ((size_t)b * 100 + ldsRow) * C_;
    xsr[tid] = v0; xsr[tid + 256] = v1; xsr[tid + 512] = v2;

    const float mu = blockReduceSum256(v0 + v1 + v2) * (1.f / C_);
    const float d0 = v0 - mu, d1 = v1 - mu, d2 = v2 - mu;
    const float var = blockReduceSum256(d0 * d0 + d1 * d1 + d2 * d2) * (1.f / C_);
    const float rs = rsqrtf(var + 1e-6f);
    __hip_bfloat16* tr = tb + ((size_t)b * 100 + ldsRow) * C_;
    tr[tid]       = __float2bfloat16(d0 * rs * lng[tid]       + lnb[tid]);
    tr[tid + 256] = __float2bfloat16(d1 * rs * lng[tid + 256] + lnb[tid + 256]);
    tr[tid + 512] = __float2bfloat16(d2 * rs * lng[tid + 512] + lnb[tid + 512]);
}

__global__ __launch_bounds__(256) void scatter_back_kernel(const float* __restrict__ xs,
                                                           const float* __restrict__ fast,
                                                           const float* __restrict__ rep,
                                                           float* __restrict__ x)
{
    const int b = blockIdx.x, t = blockIdx.y, tid = threadIdx.x;
#pragma unroll
    for (int j = 0; j < 3; ++j) {
        const int c = tid + j * 256;
        float v;
        if (t <= NKEEP)
            v = xs[((size_t)b * 100 + t) * C_ + c];
        else
            v = fast[((size_t)b * (NP_ - NKEEP) + (t - NKEEP - 1)) * C_ + c]
                + 0.5f * (xs[((size_t)b * 100 + 99) * C_ + c] - rep[(size_t)b * C_ + c]);
        x[((size_t)b * NTOK + t) * C_ + c] = v;
    }
}

// ---------------- host ----------------
extern "C" void kernel_launch(void* const* d_in, const int* in_sizes, int n_in,
                              void* d_out, int out_size, void* d_ws, size_t ws_size,
                              hipStream_t stream)
{
    (void)in_sizes; (void)n_in; (void)out_size;
    const float* x_img   = (const float*)d_in[0];
    const float* cls_tok = (const float*)d_in[1];
    const float* pos     = (const float*)d_in[2];
    const float* patch_w = (const float*)d_in[3];
    const float* patch_b = (const float*)d_in[4];
    const float* ln1_g   = (const float*)d_in[5];
    const float* ln1_b   = (const float*)d_in[6];
    const float* qk_w    = (const float*)d_in[7];
    const float* qk_b    = (const float*)d_in[8];
    const float* v_w     = (const float*)d_in[9];
    const float* v_b     = (const float*)d_in[10];
    const float* proj_w  = (const float*)d_in[11];
    const float* proj_b  = (const float*)d_in[12];
    const float* ln2_g   = (const float*)d_in[13];
    const float* ln2_b   = (const float*)d_in[14];
    const float* fc1_w   = (const float*)d_in[15];
    const float* fc1_b   = (const float*)d_in[16];
    const float* fc2_w   = (const float*)d_in[17];
    const float* fc2_b   = (const float*)d_in[18];
    const float* norm_g  = (const float*)d_in[19];
    const float* norm_b  = (const float*)d_in[20];
    const float* head_w  = (const float*)d_in[21];
    const float* head_b  = (const float*)d_in[22];

    char* base = (char*)d_ws;
    size_t off = 0;
    auto alloc = [&](size_t bytes) -> void* {
        void* p = base + off; off = (off + bytes + 255) & ~(size_t)255; return p;
    };
    float* X    = (float*)alloc((size_t)MPAD * C_ * 4);
    __hip_bfloat16* Tb   = (__hip_bfloat16*)alloc((size_t)MPAD * C_ * 2);
    __hip_bfloat16* QKVb = (__hip_bfloat16*)alloc((size_t)MPAD * RS_ * 2);
    __hip_bfloat16* Hb   = (__hip_bfloat16*)alloc((size_t)MPAD * 4 * C_ * 2);
    float* PART = (float*)alloc((size_t)2 * MPAD * C_ * 4);
    float* XS   = (float*)alloc((size_t)3200 * C_ * 4);
    float* FAST = (float*)alloc((size_t)B_ * (NP_ - NKEEP) * C_ * 4);
    float* REP  = (float*)alloc((size_t)B_ * C_ * 4);
    float* ATTN0= (float*)alloc((size_t)B_ * NH_ * NTOK * 4);
    float* CLS  = (float*)alloc((size_t)B_ * NP_ * 4);
    float* SORT = (float*)alloc((size_t)B_ * NP_ * 4);
    float* SSUM = (float*)alloc((size_t)B_ * 4);
    float* T0   = (float*)alloc((size_t)B_ * C_ * 4);
    int*   IDX  = (int*)alloc((size_t)B_ * NP_ * 4);
    float* BIASQKV = (float*)alloc((size_t)12 * RS_ * 4);
    __hip_bfloat16* WTpatch = (__hip_bfloat16*)alloc((size_t)C_ * C_ * 2);
    __hip_bfloat16* WTqkv   = (__hip_bfloat16*)alloc((size_t)12 * RS_ * C_ * 2);
    __hip_bfloat16* WTproj  = (__hip_bfloat16*)alloc((size_t)12 * C_ * C_ * 2);
    __hip_bfloat16* WTfc1   = (__hip_bfloat16*)alloc((size_t)12 * C_ * 4 * C_ * 2);
    __hip_bfloat16* WTfc2   = (__hip_bfloat16*)alloc((size_t)12 * 4 * C_ * C_ * 2);
    if (off > ws_size) return;

    __hip_bfloat16* Ob    = Hb;          // attn output aliases Hb
    __hip_bfloat16* PATCH = Hb;
    float*          PEMB  = (float*)QKVb;
    const size_t PSTRIDE = (size_t)MPAD * C_;

    const dim3 blk(256);

    // ---- weight transposes (fp32 [K][N] -> bf16 [N][K]) ----
    transpose_bf16_kernel<<<dim3(24, 24, 1), blk, 0, stream>>>(patch_w, WTpatch, C_, C_, (long long)C_ * C_, 0);
    transpose_bf16_kernel<<<dim3(48, 24, 12), blk, 0, stream>>>(qk_w, WTqkv, C_, 2 * C_, (long long)RS_ * C_, 0);
    transpose_bf16_kernel<<<dim3(24, 24, 12), blk, 0, stream>>>(v_w, WTqkv, C_, C_, (long long)RS_ * C_, (long long)2 * C_ * C_);
    transpose_bf16_kernel<<<dim3(24, 24, 12), blk, 0, stream>>>(proj_w, WTproj, C_, C_, (long long)C_ * C_, 0);
    transpose_bf16_kernel<<<dim3(96, 24, 12), blk, 0, stream>>>(fc1_w, WTfc1, C_, 4 * C_, (long long)4 * C_ * C_, 0);
    transpose_bf16_kernel<<<dim3(24, 96, 12), blk, 0, stream>>>(fc2_w, WTfc2, 4 * C_, C_, (long long)4 * C_ * C_, 0);
    concat_bias_kernel<<<(12 * RS_ + 255) / 256, blk, 0, stream>>>(qk_b, v_b, BIASQKV);

    auto runBlock = [&](int i, float* xb, int Nt, bool skipLn1) {
        const int M = B_ * Nt;
        const int mt = (M + 127) >> 7;
        const int mt64 = (M + 63) >> 6;
        const int qtiles = (Nt + 63) >> 6;
        if (!skipLn1)
            ln_kernel<<<(M + 3) / 4, blk, 0, stream>>>(xb, ln1_g + i * C_, ln1_b + i * C_, Tb, nullptr, C_, M);
        gemm_bf16_kernel<0, 0><<<dim3(RS_ / 128, mt), blk, 0, stream>>>(
            Tb, WTqkv + (size_t)i * RS_ * C_, BIASQKV + (size_t)i * RS_, nullptr, nullptr, QKVb, C_, RS_);
        if (Nt == NTOK)
            attn_mfma_kernel<14><<<dim3(B_ * NH_, qtiles), blk, 0, stream>>>(QKVb, Ob, ATTN0, Nt);
        else
            attn_mfma_kernel<8><<<dim3(B_ * NH_, qtiles), blk, 0, stream>>>(QKVb, Ob, ATTN0, Nt);
        gemm_half_kernel<1><<<dim3(6, mt64), blk, 0, stream>>>(
            Ob, WTproj + (size_t)i * C_ * C_, proj_b + (size_t)i * C_, xb, xb, C_, C_, 1, 0);
        ln_kernel<<<(M + 3) / 4, blk, 0, stream>>>(xb, ln2_g + i * C_, ln2_b + i * C_, Tb, nullptr, C_, M);
        gemm_bf16_kernel<1, 0><<<dim3(24, mt), blk, 0, stream>>>(
            Tb, WTfc1 + (size_t)i * C_ * 4 * C_, fc1_b + (size_t)i * 4 * C_, nullptr, nullptr, Hb, C_, 4 * C_);
        // fc2: split-K=2 partial + deterministic combine
        gemm_half_kernel<3><<<dim3(6, mt64, 2), blk, 0, stream>>>(
            Hb, WTfc2 + (size_t)i * 4 * C_ * C_, nullptr, nullptr, PART, 4 * C_, C_, 2, PSTRIDE);
        combine_kernel<1><<<(M * C_ / 4 + 255) / 256, blk, 0, stream>>>(
            PART, PSTRIDE, fc2_b + (size_t)i * C_, xb, xb, M * C_, C_);
    };

    // ---- patch embedding ----
    patchify_kernel<<<B_ * NP_, blk, 0, stream>>>(x_img, PATCH);
    gemm_half_kernel<2><<<dim3(6, 98), blk, 0, stream>>>(
        PATCH, WTpatch, patch_b, nullptr, PEMB, C_, C_, 1, 0);
    assemble_x_kernel<<<dim3(B_, NTOK), blk, 0, stream>>>(PEMB, cls_tok, pos, X);

    // ---- 12 transformer blocks ----
    for (int i = 0; i < 12; ++i) {
        if (i < 4) {
            runBlock(i, X, NTOK, false);
            row_cls_ema_kernel<<<B_, blk, 0, stream>>>(ATTN0, CLS, i == 0 ? 1 : 0);
        } else {
            rank_kernel<<<B_, blk, 0, stream>>>(CLS, IDX, SORT, SSUM);
            build_xs_kernel<<<dim3(B_, 198), blk, 0, stream>>>(
                X, IDX, SORT, SSUM, XS, FAST, REP, ln1_g + i * C_, ln1_b + i * C_, Tb);
            runBlock(i, XS, 100, true);
            scatter_back_kernel<<<dim3(B_, NTOK), blk, 0, stream>>>(XS, FAST, REP, X);
            row_cls_prune_kernel<<<B_, blk, 0, stream>>>(ATTN0, SORT, CLS);
        }
    }

    // ---- final LN (token 0 only) + head (fp32 exact) ----
    ln_kernel<<<8, blk, 0, stream>>>(X, norm_g, norm_b, nullptr, T0, (long long)NTOK * C_, B_);
    head_kernel<<<dim3(4, B_), blk, 0, stream>>>(T0, head_w, head_b, (float*)d_out);
}

// Round 16
// 2450.094 us; speedup vs baseline: 1.0113x; 1.0113x over previous
//
#include <hip/hip_runtime.h>
#include <hip/hip_bf16.h>
#include <stdint.h>

#define B_ 32
#define C_ 768
#define NH_ 12
#define HD_ 64
#define NP_ 196
#define NTOK 197
#define NKEEP 98
#define NCLS_ 1000
#define MPAD 6400
#define RS_ (3 * C_)   // QKV row stride

typedef __bf16 bf16x8 __attribute__((ext_vector_type(8)));
typedef float f32x4 __attribute__((ext_vector_type(4)));

// ---------------- block reduction (256 threads) ----------------
__device__ __forceinline__ float blockReduceSum256(float v) {
    __shared__ float red[4];
    const int lane = threadIdx.x & 63, w = threadIdx.x >> 6;
#pragma unroll
    for (int off = 32; off; off >>= 1) v += __shfl_down(v, off);
    __syncthreads();
    if (lane == 0) red[w] = v;
    __syncthreads();
    return red[0] + red[1] + red[2] + red[3];
}

// ---------------- async global->LDS (16B per lane) ----------------
__device__ __forceinline__ void gload16(void* lds, const void* g) {
    __builtin_amdgcn_global_load_lds(
        (const __attribute__((address_space(1))) void*)g,
        (__attribute__((address_space(3))) void*)lds,
        16, 0, 0);
}

// ---------------- patchify: (B,3,224,224) -> bf16 (B*196, 768) ----------------
__global__ __launch_bounds__(256) void patchify_kernel(const float* __restrict__ img,
                                                       __hip_bfloat16* __restrict__ patches)
{
    const int bp = blockIdx.x;
    const int b = bp / NP_, p = bp % NP_;
    const int gy = p / 14, gx = p % 14;
    const int tid = threadIdx.x;
#pragma unroll
    for (int j = 0; j < 3; ++j) {
        const int e = tid + j * 256;
        const int c = e >> 8, rem = e & 255, py = rem >> 4, px = rem & 15;
        patches[(size_t)bp * C_ + e] = __float2bfloat16(
            img[(((size_t)b * 3 + c) * 224 + gy * 16 + py) * 224 + gx * 16 + px]);
    }
}

// ---------------- x = concat(cls, pemb) + pos ----------------
__global__ __launch_bounds__(256) void assemble_x_kernel(const float* __restrict__ pemb,
                                                         const float* __restrict__ cls_tok,
                                                         const float* __restrict__ pos,
                                                         float* __restrict__ x)
{
    const int b = blockIdx.x, t = blockIdx.y, tid = threadIdx.x;
#pragma unroll
    for (int j = 0; j < 3; ++j) {
        const int c = tid + j * 256;
        const float v = (t == 0) ? cls_tok[c] : pemb[((size_t)b * NP_ + (t - 1)) * C_ + c];
        x[((size_t)b * NTOK + t) * C_ + c] = v + pos[(size_t)t * C_ + c];
    }
}

// ---------------- layernorm: wave per row ----------------
__global__ __launch_bounds__(256) void ln_kernel(const float* __restrict__ x,
                                                 const float* __restrict__ g,
                                                 const float* __restrict__ b,
                                                 __hip_bfloat16* outB, float* outF,
                                                 long long inRowStride, int nRows)
{
    const int row = (blockIdx.x << 2) + (threadIdx.x >> 6);
    const int lane = threadIdx.x & 63;
    if (row >= nRows) return;
    const float* xr = x + (size_t)row * inRowStride;
    float4 v0 = *(const float4*)(xr + (lane << 2));
    float4 v1 = *(const float4*)(xr + 256 + (lane << 2));
    float4 v2 = *(const float4*)(xr + 512 + (lane << 2));
    float s = v0.x + v0.y + v0.z + v0.w + v1.x + v1.y + v1.z + v1.w
            + v2.x + v2.y + v2.z + v2.w;
#pragma unroll
    for (int off = 1; off < 64; off <<= 1) s += __shfl_xor(s, off);
    const float mu = s * (1.f / C_);
    float q = 0.f;
    {
        float d;
        d = v0.x - mu; q += d * d; d = v0.y - mu; q += d * d;
        d = v0.z - mu; q += d * d; d = v0.w - mu; q += d * d;
        d = v1.x - mu; q += d * d; d = v1.y - mu; q += d * d;
        d = v1.z - mu; q += d * d; d = v1.w - mu; q += d * d;
        d = v2.x - mu; q += d * d; d = v2.y - mu; q += d * d;
        d = v2.z - mu; q += d * d; d = v2.w - mu; q += d * d;
    }
#pragma unroll
    for (int off = 1; off < 64; off <<= 1) q += __shfl_xor(q, off);
    const float rs = rsqrtf(q * (1.f / C_) + 1e-6f);
    const float4 vv[3] = {v0, v1, v2};
#pragma unroll
    for (int j = 0; j < 3; ++j) {
        const int cbase = (j << 8) + (lane << 2);
        const float4 gv = *(const float4*)(g + cbase);
        const float4 bv = *(const float4*)(b + cbase);
        float o0 = (vv[j].x - mu) * rs * gv.x + bv.x;
        float o1 = (vv[j].y - mu) * rs * gv.y + bv.y;
        float o2 = (vv[j].z - mu) * rs * gv.z + bv.z;
        float o3 = (vv[j].w - mu) * rs * gv.w + bv.w;
        if (outB) {
            union { unsigned short us[4]; uint2 u; } pk;
            __hip_bfloat16 h;
            h = __float2bfloat16(o0); pk.us[0] = *(unsigned short*)&h;
            h = __float2bfloat16(o1); pk.us[1] = *(unsigned short*)&h;
            h = __float2bfloat16(o2); pk.us[2] = *(unsigned short*)&h;
            h = __float2bfloat16(o3); pk.us[3] = *(unsigned short*)&h;
            *(uint2*)((unsigned short*)outB + (size_t)row * C_ + cbase) = pk.u;
        }
        if (outF) {
            float4 o; o.x = o0; o.y = o1; o.z = o2; o.w = o3;
            *(float4*)(outF + (size_t)row * C_ + cbase) = o;
        }
    }
}

// ---------------- weight transpose+convert: fp32 [K][N] -> bf16 [N][K] ----------------
__global__ __launch_bounds__(256) void transpose_bf16_kernel(const float* __restrict__ W,
                                                             __hip_bfloat16* __restrict__ Wt,
                                                             int K, int N,
                                                             long long outLstride, long long outOff)
{
    __shared__ float tile[32][33];
    const size_t loffIn = (size_t)blockIdx.z * K * N;
    const size_t loffOut = (size_t)blockIdx.z * outLstride + outOff;
    const int k0 = blockIdx.y << 5, n0 = blockIdx.x << 5;
    const int tid = threadIdx.x;
#pragma unroll
    for (int e = tid; e < 1024; e += 256) {
        const int r = e >> 5, c = e & 31;
        tile[r][c] = W[loffIn + (size_t)(k0 + r) * N + n0 + c];
    }
    __syncthreads();
#pragma unroll
    for (int e = tid; e < 1024; e += 256) {
        const int r = e >> 5, c = e & 31;
        Wt[loffOut + (size_t)(n0 + r) * K + k0 + c] = __float2bfloat16(tile[c][r]);
    }
}

// ---------------- concat qk_b / v_b into per-layer 2304 bias ----------------
__global__ __launch_bounds__(256) void concat_bias_kernel(const float* __restrict__ qk_b,
                                                          const float* __restrict__ v_b,
                                                          float* __restrict__ out)
{
    const int i = blockIdx.x * 256 + threadIdx.x;
    if (i < 12 * RS_) {
        const int l = i / RS_, c = i % RS_;
        out[i] = (c < 2 * C_) ? qk_b[l * 2 * C_ + c] : v_b[l * C_ + (c - 2 * C_)];
    }
}

// ---------------- bf16 MFMA GEMM: 128x128 tile, BK=32, double-buffered, 32KB LDS ----------------
// (round-10 proven: pair-line layout, counted vmcnt(4), launch_bounds(256,4))
template<int GELU, int OMODE>
__global__ __launch_bounds__(256, 4) void gemm_bf16_kernel(const __hip_bfloat16* __restrict__ A,
                                                           const __hip_bfloat16* __restrict__ Bt,
                                                           const float* __restrict__ bias,
                                                           const float* __restrict__ res,
                                                           float* __restrict__ outF,
                                                           __hip_bfloat16* __restrict__ outB,
                                                           int K, int N)
{
    __shared__ __align__(16) unsigned short sMem[16384];  // 32KB
    const int tid = threadIdx.x;
    const int wv = tid >> 6, ln = tid & 63;

    const int nwg = gridDim.x * gridDim.y;
    int lid = blockIdx.y * gridDim.x + blockIdx.x;
    {
        const int q = nwg >> 3, r = nwg & 7;
        const int xcd = lid & 7, lq = lid >> 3;
        lid = (xcd < r ? xcd * (q + 1) : r * (q + 1) + (xcd - r) * q) + lq;
    }
    const int bn = (lid % gridDim.x) << 7;
    const int bm = (lid / gridDim.x) << 7;

    const int wr = wv >> 1, wc = wv & 1;
    const int ln15 = ln & 15, lhi = ln >> 4;

    int offA[2], offB[2];
#pragma unroll
    for (int i = 0; i < 2; ++i) {
        const int s = (i << 8) + tid;
        const int L = s >> 3, cp = (s & 7) ^ (L & 7);
        offA[i] = (bm + (L << 1) + (cp >> 2)) * K + ((cp & 3) << 3);
        offB[i] = (bn + (L << 1) + (cp >> 2)) * K + ((cp & 3) << 3);
    }

    const unsigned ldsBase =
        (unsigned)(size_t)(__attribute__((address_space(3))) unsigned short*)&sMem[0];
    unsigned aOff[4], bOff[4];
#pragma unroll
    for (int m = 0; m < 4; ++m) {
        const int r = (wr << 6) + (m << 4) + ln15;
        const int L = r >> 1;
        const int pc = (((r & 1) << 2) + lhi) ^ (L & 7);
        aOff[m] = (unsigned)((L << 7) + (pc << 4));
    }
#pragma unroll
    for (int n = 0; n < 4; ++n) {
        const int r = (wc << 6) + (n << 4) + ln15;
        const int L = r >> 1;
        const int pc = (((r & 1) << 2) + lhi) ^ (L & 7);
        bOff[n] = (unsigned)(8192 + (L << 7) + (pc << 4));
    }

    f32x4 acc[4][4] = {};

    auto stage = [&](int bufByte, int kt) {
        const int k0 = kt << 5;
        unsigned short* base = sMem + (bufByte >> 1);
        gload16(base + ((0 * 256 + (wv << 6)) << 3), A + offA[0] + k0);
        gload16(base + ((1 * 256 + (wv << 6)) << 3), A + offA[1] + k0);
        gload16(base + 4096 + ((0 * 256 + (wv << 6)) << 3), Bt + offB[0] + k0);
        gload16(base + 4096 + ((1 * 256 + (wv << 6)) << 3), Bt + offB[1] + k0);
    };
    auto compute = [&](unsigned bufOff) {
        bf16x8 a[4], b[4];
#pragma unroll
        for (int m = 0; m < 4; ++m)
            asm volatile("ds_read_b128 %0, %1" : "=v"(a[m]) : "v"(ldsBase + bufOff + aOff[m]));
#pragma unroll
        for (int n = 0; n < 4; ++n)
            asm volatile("ds_read_b128 %0, %1" : "=v"(b[n]) : "v"(ldsBase + bufOff + bOff[n]));
        asm volatile("s_waitcnt lgkmcnt(0)" ::: "memory");
        __builtin_amdgcn_sched_barrier(0);
#pragma unroll
        for (int m = 0; m < 4; ++m)
#pragma unroll
            for (int n = 0; n < 4; ++n)
                acc[m][n] = __builtin_amdgcn_mfma_f32_16x16x32_bf16(a[m], b[n], acc[m][n], 0, 0, 0);
    };

    const int ntiles = K >> 5;
    stage(0, 0);
    asm volatile("s_waitcnt vmcnt(0)" ::: "memory");
    __builtin_amdgcn_s_barrier();
    int t = 0;
    for (; t + 2 < ntiles; t += 2) {
        stage(16384, t + 1);
        asm volatile("s_waitcnt vmcnt(4)" ::: "memory");
        __builtin_amdgcn_s_barrier();
        compute(0u);
        __builtin_amdgcn_s_barrier();
        stage(0, t + 2);
        asm volatile("s_waitcnt vmcnt(4)" ::: "memory");
        __builtin_amdgcn_s_barrier();
        compute(16384u);
        __builtin_amdgcn_s_barrier();
    }
    stage(16384, ntiles - 1);
    asm volatile("s_waitcnt vmcnt(4)" ::: "memory");
    __builtin_amdgcn_s_barrier();
    compute(0u);
    __builtin_amdgcn_s_barrier();
    asm volatile("s_waitcnt vmcnt(0)" ::: "memory");
    __builtin_amdgcn_s_barrier();
    compute(16384u);
    __syncthreads();

    if (OMODE == 0) {
        unsigned short* sOut = sMem;
#pragma unroll
        for (int n = 0; n < 4; ++n) {
            const int col = (wc << 6) + (n << 4) + ln15;
            const float bv = bias[bn + col];
#pragma unroll
            for (int m = 0; m < 4; ++m) {
                const int row0 = (wr << 6) + (m << 4) + (lhi << 2);
#pragma unroll
                for (int r = 0; r < 4; ++r) {
                    float x = acc[m][n][r] + bv;
                    if (GELU) x = 0.5f * x * (1.f + erff(x * 0.70710678118654752f));
                    const __hip_bfloat16 hb = __float2bfloat16(x);
                    sOut[(row0 + r) * 128 + col] = *(const unsigned short*)&hb;
                }
            }
        }
        __syncthreads();
#pragma unroll
        for (int i = 0; i < 8; ++i) {
            const int chunk = (i << 8) + tid;
            const int row = chunk >> 4, c8 = (chunk & 15) << 3;
            *(uint4*)((unsigned short*)outB + (size_t)(bm + row) * N + bn + c8) =
                *(const uint4*)(sOut + row * 128 + c8);
        }
    } else {
#pragma unroll
        for (int n = 0; n < 4; ++n) {
            const int gcn = bn + (wc << 6) + (n << 4) + ln15;
            const float bv = bias[gcn];
#pragma unroll
            for (int m = 0; m < 4; ++m) {
                const int gr0 = bm + (wr << 6) + (m << 4) + (lhi << 2);
                f32x4 v = acc[m][n];
#pragma unroll
                for (int r = 0; r < 4; ++r) {
                    const size_t o = (size_t)(gr0 + r) * N + gcn;
                    float x = v[r] + bv;
                    if (OMODE == 1) x += res[o];
                    outF[o] = x;
                }
            }
        }
    }
}

// ---------------- HALF bf16 MFMA GEMM: 64x128 tile, BK=32, 4-stage REGISTER-PREFETCH ----------------
// Per step: vmcnt(3) [tile t+1 landed, 2 iters in flight] -> barrier ->
// stage(t+3) -> ds_read tile t+1 frags into ping-pong regs -> lgkmcnt(6)
// [tile t's frags, read LAST step, retired: no wait] -> MFMA(tile t).
// 48KB LDS. OMODE 1: f32 + res; 2: f32. ntiles % 4 == 0 (24, 96).
#define HSTEP(VMC, PBUF, SBUF, CA, CB, NA, NB, DOSTAGE, DOPRE, KS)             \
    {                                                                          \
        asm volatile("s_waitcnt vmcnt(" VMC ")" ::: "memory");                 \
        __builtin_amdgcn_s_barrier();                                          \
        if (DOSTAGE) stage((SBUF) * 6144, (KS));                               \
        if (DOPRE) {                                                           \
            _Pragma("unroll")                                                  \
            for (int m_ = 0; m_ < 2; ++m_)                                     \
                asm volatile("ds_read_b128 %0, %1"                             \
                    : "=v"(NA[m_]) : "v"(ldsBase + (PBUF) * 12288u + aOff[m_]));\
            _Pragma("unroll")                                                  \
            for (int n_ = 0; n_ < 4; ++n_)                                     \
                asm volatile("ds_read_b128 %0, %1"                             \
                    : "=v"(NB[n_]) : "v"(ldsBase + (PBUF) * 12288u + bOff[n_]));\
            asm volatile("s_waitcnt lgkmcnt(6)" ::: "memory");                 \
        } else {                                                               \
            asm volatile("s_waitcnt lgkmcnt(0)" ::: "memory");                 \
        }                                                                      \
        __builtin_amdgcn_sched_barrier(0);                                     \
        _Pragma("unroll")                                                      \
        for (int m_ = 0; m_ < 2; ++m_)                                         \
            _Pragma("unroll")                                                  \
            for (int n_ = 0; n_ < 4; ++n_)                                     \
                acc[m_][n_] = __builtin_amdgcn_mfma_f32_16x16x32_bf16(         \
                    CA[m_], CB[n_], acc[m_][n_], 0, 0, 0);                     \
    }

template<int OMODE>
__global__ __launch_bounds__(256, 4) void gemm_half_kernel(const __hip_bfloat16* __restrict__ A,
                                                           const __hip_bfloat16* __restrict__ Bt,
                                                           const float* __restrict__ bias,
                                                           const float* __restrict__ res,
                                                           float* __restrict__ outF,
                                                           int K, int N)
{
    __shared__ __align__(16) unsigned short sMem[4 * 6144];  // 48KB: {A 4KB, B 8KB} x 4
    const int tid = threadIdx.x;
    const int wv = tid >> 6, ln = tid & 63;

    const int nwg = gridDim.x * gridDim.y;
    int lid = blockIdx.y * gridDim.x + blockIdx.x;
    {
        const int q = nwg >> 3, r = nwg & 7;
        const int xcd = lid & 7, lq = lid >> 3;
        lid = (xcd < r ? xcd * (q + 1) : r * (q + 1) + (xcd - r) * q) + lq;
    }
    const int bn = (lid % gridDim.x) << 7;
    const int bm = (lid / gridDim.x) << 6;

    const int wr = wv >> 1, wc = wv & 1;          // wave tile rows wr*32, cols wc*64
    const int ln15 = ln & 15, lhi = ln >> 4;

    int offA, offB[2];
    {
        const int L = tid >> 3, cp = (tid & 7) ^ (L & 7);
        offA = (bm + (L << 1) + (cp >> 2)) * K + ((cp & 3) << 3);
    }
#pragma unroll
    for (int i = 0; i < 2; ++i) {
        const int s = (i << 8) + tid;
        const int L = s >> 3, cp = (s & 7) ^ (L & 7);
        offB[i] = (bn + (L << 1) + (cp >> 2)) * K + ((cp & 3) << 3);
    }

    const unsigned ldsBase =
        (unsigned)(size_t)(__attribute__((address_space(3))) unsigned short*)&sMem[0];
    unsigned aOff[2], bOff[4];
#pragma unroll
    for (int m = 0; m < 2; ++m) {
        const int r = (wr << 5) + (m << 4) + ln15;
        const int L = r >> 1;
        const int pc = (((r & 1) << 2) + lhi) ^ (L & 7);
        aOff[m] = (unsigned)((L << 7) + (pc << 4));
    }
#pragma unroll
    for (int n = 0; n < 4; ++n) {
        const int r = (wc << 6) + (n << 4) + ln15;
        const int L = r >> 1;
        const int pc = (((r & 1) << 2) + lhi) ^ (L & 7);
        bOff[n] = (unsigned)(4096 + (L << 7) + (pc << 4));   // B at byte 4096 within buf
    }

    f32x4 acc[2][4] = {};
    bf16x8 r0a[2], r0b[4], r1a[2], r1b[4];

    auto stage = [&](int bufUShort, int kt) {
        const int k0 = kt << 5;
        unsigned short* base = sMem + bufUShort;
        gload16(base + ((wv << 6) << 3), A + offA + k0);
        gload16(base + 2048 + ((0 * 256 + (wv << 6)) << 3), Bt + offB[0] + k0);
        gload16(base + 2048 + ((1 * 256 + (wv << 6)) << 3), Bt + offB[1] + k0);
    };

    const int ntiles = K >> 5;   // 24 or 96 (divisible by 4, >= 8)
    stage(0, 0);
    stage(6144, 1);
    stage(12288, 2);
    asm volatile("s_waitcnt vmcnt(6)" ::: "memory");   // tile 0 landed
    __builtin_amdgcn_s_barrier();
#pragma unroll
    for (int m = 0; m < 2; ++m)
        asm volatile("ds_read_b128 %0, %1" : "=v"(r0a[m]) : "v"(ldsBase + aOff[m]));
#pragma unroll
    for (int n = 0; n < 4; ++n)
        asm volatile("ds_read_b128 %0, %1" : "=v"(r0b[n]) : "v"(ldsBase + bOff[n]));

    int t = 0;
    for (; t < ntiles - 4; t += 4) {
        HSTEP("3", 1, 3, r0a, r0b, r1a, r1b, true, true, t + 3);
        HSTEP("3", 2, 0, r1a, r1b, r0a, r0b, true, true, t + 4);
        HSTEP("3", 3, 1, r0a, r0b, r1a, r1b, true, true, t + 5);
        HSTEP("3", 0, 2, r1a, r1b, r0a, r0b, true, true, t + 6);
    }
    // tail: t == ntiles-4 (buffer phase 0, cur reg r0)
    HSTEP("3", 1, 3, r0a, r0b, r1a, r1b, true,  true,  t + 3);   // stages tile nt-1
    HSTEP("3", 2, 0, r1a, r1b, r0a, r0b, false, true,  0);
    HSTEP("0", 3, 0, r0a, r0b, r1a, r1b, false, true,  0);
    HSTEP("0", 0, 0, r1a, r1b, r0a, r0b, false, false, 0);

#pragma unroll
    for (int n = 0; n < 4; ++n) {
        const int gcn = bn + (wc << 6) + (n << 4) + ln15;
        const float bv = bias[gcn];
#pragma unroll
        for (int m = 0; m < 2; ++m) {
            const int gr0 = bm + (wr << 5) + (m << 4) + (lhi << 2);
            f32x4 v = acc[m][n];
#pragma unroll
            for (int r = 0; r < 4; ++r) {
                const size_t o = (size_t)(gr0 + r) * N + gcn;
                float x = v[r] + bv;
                if (OMODE == 1) x += res[o];
                outF[o] = x;
            }
        }
    }
}

// ---------------- head: out[m][n] = A[m] . W[:,n] + bias (fp32 exact) ----------------
__global__ __launch_bounds__(256) void head_kernel(const float* __restrict__ A,
                                                   const float* __restrict__ W,
                                                   const float* __restrict__ bias,
                                                   float* __restrict__ out)
{
    const int n = blockIdx.x * 256 + threadIdx.x;
    const int m = blockIdx.y;
    if (n >= NCLS_) return;
    const float* a = A + (size_t)m * C_;
    float s = 0.f;
#pragma unroll 8
    for (int k = 0; k < C_; ++k) s = fmaf(a[k], W[(size_t)k * NCLS_ + n], s);
    out[(size_t)m * NCLS_ + n] = s + bias[n];
}

// ---------------- MFMA attention (QKV fused input, row stride 3C) ----------------
template<int NT16>
__global__ __launch_bounds__(256) void attn_mfma_kernel(const __hip_bfloat16* __restrict__ qkv,
                                                        __hip_bfloat16* __restrict__ o,
                                                        float* __restrict__ attn0,
                                                        int Nt)
{
    constexpr int NPAD = NT16 * 16;
    constexpr int PSW = (((NPAD / 8) & 7) == 0) ? 7 : 3;
    constexpr int VSW = 7;
    constexpr int PROWB = NPAD * 2 + 16;
    constexpr int VROWB = (NPAD == 224) ? 528 : 272;
    __shared__ unsigned short sK[NPAD * 64 + 512];
    __shared__ unsigned short sV[32 * VROWB];

    const int bh = blockIdx.x;
    const int b = bh / NH_, h = bh % NH_;
    const int qtile = blockIdx.y;
    const int tid = threadIdx.x, ln = tid & 63, wv = tid >> 6;
    const int ln15 = ln & 15, lhi = ln >> 4;
    const __hip_bfloat16* qkbase = qkv + (size_t)b * Nt * RS_;

#pragma unroll
    for (int it = 0; it < NPAD * 8 / 256; ++it) {
        const int p = it * 256 + tid;
        int key = p >> 3;
        const int c = (p & 7) ^ (key & 7);
        if (key >= Nt) key = Nt - 1;
        unsigned short* dst = sK + (size_t)(it * 256 + (wv << 6)) * 8;
        gload16(dst, qkbase + (size_t)key * RS_ + C_ + (h << 6) + (c << 3));
    }
#pragma unroll
    for (int it = 0; it < NPAD * 8 / 256; ++it) {
        const int e = it * 256 + tid;
        const int key = e >> 3, dc = e & 7;
        union { uint4 u; unsigned short us[8]; } val;
        val.u = make_uint4(0u, 0u, 0u, 0u);
        if (key < Nt)
            val.u = *(const uint4*)(qkbase + (size_t)key * RS_ + 2 * C_ + (h << 6) + (dc << 3));
        const int kc = key >> 3, kb = (key & 7) << 1;
#pragma unroll
        for (int j = 0; j < 8; ++j) {
            const int d = (dc << 3) + j;
            *(unsigned short*)((char*)sV + d * VROWB + ((kc ^ ((d >> 3) & VSW)) << 4) + kb) = val.us[j];
        }
    }
    const int qbase = qtile * 64 + (wv << 4);
    int qrow = qbase + ln15; if (qrow >= Nt) qrow = Nt - 1;
    const __hip_bfloat16* qp = qkbase + (size_t)qrow * RS_ + (h << 6) + (lhi << 3);
    const bf16x8 qf0 = *(const bf16x8*)qp;
    const bf16x8 qf1 = *(const bf16x8*)(qp + 32);
    __syncthreads();

    f32x4 sc[NT16];
#pragma unroll
    for (int t = 0; t < NT16; ++t) {
        const int key = (t << 4) + ln15;
        const unsigned short* kr = sK + (size_t)key * 64;
        const bf16x8 k0 = *(const bf16x8*)(kr + ((lhi ^ (key & 7)) << 3));
        const bf16x8 k1 = *(const bf16x8*)(kr + (((4 + lhi) ^ (key & 7)) << 3));
        f32x4 a = {0.f, 0.f, 0.f, 0.f};
        a = __builtin_amdgcn_mfma_f32_16x16x32_bf16(k0, qf0, a, 0, 0, 0);
        a = __builtin_amdgcn_mfma_f32_16x16x32_bf16(k1, qf1, a, 0, 0, 0);
        sc[t] = a;
    }
    __syncthreads();

    float mx = -1e30f;
#pragma unroll
    for (int t = 0; t < NT16; ++t)
#pragma unroll
        for (int r = 0; r < 4; ++r) {
            const int key = (t << 4) + (lhi << 2) + r;
            const float v = (key < Nt) ? sc[t][r] * 0.125f : -1e30f;
            sc[t][r] = v;
            mx = fmaxf(mx, v);
        }
    mx = fmaxf(mx, __shfl_xor(mx, 16));
    mx = fmaxf(mx, __shfl_xor(mx, 32));
    float sum = 0.f;
#pragma unroll
    for (int t = 0; t < NT16; ++t)
#pragma unroll
        for (int r = 0; r < 4; ++r) {
            const float e = expf(sc[t][r] - mx);
            sc[t][r] = e; sum += e;
        }
    sum += __shfl_xor(sum, 16);
    sum += __shfl_xor(sum, 32);
    const float inv = 1.f / sum;

    char* Pw = (char*)sK + wv * (16 * PROWB);
    const bool isQ0 = (qtile == 0) && (wv == 0) && (ln15 == 0);
#pragma unroll
    for (int t = 0; t < NT16; ++t) {
        union { unsigned short us[4]; uint2 u2; } pk;
#pragma unroll
        for (int r = 0; r < 4; ++r) {
            const float p = sc[t][r] * inv;
            const __hip_bfloat16 hb = __float2bfloat16(p);
            pk.us[r] = *(const unsigned short*)&hb;
            if (isQ0) {
                const int key = (t << 4) + (lhi << 2) + r;
                if (key < Nt) attn0[(size_t)bh * NTOK + key] = p;
            }
        }
        const int chunk = ((t << 1) + (lhi >> 1)) ^ (ln15 & PSW);
        *(uint2*)(Pw + ln15 * PROWB + (chunk << 4) + ((lhi & 1) << 3)) = pk.u2;
    }
    __syncthreads();

    f32x4 oa[4] = {};
#pragma unroll
    for (int s = 0; s < NPAD / 32; ++s) {
        const bf16x8 pf = *(const bf16x8*)(Pw + ln15 * PROWB +
                                           ((((s << 2) + lhi) ^ (ln15 & PSW)) << 4));
#pragma unroll
        for (int n = 0; n < 4; ++n) {
            const int d = (n << 4) + ln15;
            const bf16x8 vf = *(const bf16x8*)((char*)sV + d * VROWB +
                                               ((((s << 2) + lhi) ^ ((d >> 3) & VSW)) << 4));
            oa[n] = __builtin_amdgcn_mfma_f32_16x16x32_bf16(pf, vf, oa[n], 0, 0, 0);
        }
    }
#pragma unroll
    for (int n = 0; n < 4; ++n)
#pragma unroll
        for (int r = 0; r < 4; ++r) {
            const int qq = qbase + (lhi << 2) + r;
            if (qq < Nt)
                o[((size_t)b * Nt + qq) * C_ + (h << 6) + (n << 4) + ln15] =
                    __float2bfloat16(oa[n][r]);
        }
}

// ---------------- row + cls EMA (full layers) ----------------
__global__ __launch_bounds__(256) void row_cls_ema_kernel(const float* __restrict__ attn0,
                                                          float* __restrict__ cls, int first)
{
    const int b = blockIdx.x, t = threadIdx.x;
    if (t < NP_) {
        float s = 0.f;
#pragma unroll
        for (int h = 0; h < NH_; ++h) s += attn0[((size_t)(b * NH_ + h)) * NTOK + 1 + t];
        const int i = b * NP_ + t;
        cls[i] = first ? s : 0.5f * cls[i] + 0.5f * s;
    }
}

// ---------------- row + cls update (pruned layers) ----------------
__global__ __launch_bounds__(256) void row_cls_prune_kernel(const float* __restrict__ attn0,
                                                            const float* __restrict__ sorted,
                                                            float* __restrict__ cls)
{
    const int b = blockIdx.x, t = threadIdx.x;
    if (t < NP_) {
        float sv = sorted[b * NP_ + t];
        if (t < NKEEP) {
            float s = 0.f;
#pragma unroll
            for (int h = 0; h < NH_; ++h) s += attn0[((size_t)(b * NH_ + h)) * NTOK + 1 + t];
            sv = 0.5f * sv + 0.5f * s;
        }
        cls[b * NP_ + t] = sv;
    }
}

// ---------------- stable descending rank-sort ----------------
__global__ __launch_bounds__(256) void rank_kernel(const float* __restrict__ cls,
                                                   int* __restrict__ idx,
                                                   float* __restrict__ sorted,
                                                   float* __restrict__ ssum)
{
    __shared__ float sv[NP_];
    const int b = blockIdx.x, t = threadIdx.x;
    if (t < NP_) sv[t] = cls[b * NP_ + t];
    __syncthreads();
    float val = 0.f; int r = NP_;
    if (t < NP_) {
        val = sv[t];
        r = 0;
        for (int j = 0; j < NP_; ++j) {
            const float vj = sv[j];
            r += (vj > val || (vj == val && j < t)) ? 1 : 0;
        }
        idx[b * NP_ + r] = t;
        sorted[b * NP_ + r] = val;
    }
    const float contrib = (t < NP_ && r >= NKEEP) ? val : 0.f;
    const float tot = blockReduceSum256(contrib);
    if (t == 0) ssum[b] = tot;
}

// ---------------- build xs / fast / rep, with FUSED LN1 -> Tb ----------------
__global__ __launch_bounds__(256) void build_xs_kernel(const float* __restrict__ x,
                                                       const int* __restrict__ idx,
                                                       const float* __restrict__ sorted,
                                                       const float* __restrict__ ssum,
                                                       float* __restrict__ xs,
                                                       float* __restrict__ fast,
                                                       float* __restrict__ rep,
                                                       const float* __restrict__ lng,
                                                       const float* __restrict__ lnb,
                                                       __hip_bfloat16* __restrict__ tb)
{
    const int b = blockIdx.x, t = blockIdx.y, tid = threadIdx.x;
    const float* xb = x + (size_t)b * NTOK * C_;

    float v0, v1, v2;
    int ldsRow = -1;

    if (t == 0) {
        v0 = xb[tid]; v1 = xb[tid + 256]; v2 = xb[tid + 512];
        ldsRow = 0;
    } else if (t <= NKEEP) {
        const int src = 1 + idx[b * NP_ + (t - 1)];
        const float* xr = xb + (size_t)src * C_;
        v0 = xr[tid]; v1 = xr[tid + 256]; v2 = xr[tid + 512];
        ldsRow = t;
    } else if (t == NKEEP + 1) {
        const float inv = 1.f / ssum[b];
        float a0 = 0.f, a1 = 0.f, a2 = 0.f;
        for (int jj = 0; jj < NP_ - NKEEP; ++jj) {
            const int src = 1 + idx[b * NP_ + NKEEP + jj];
            const float wgt = sorted[b * NP_ + NKEEP + jj];
            const float* xr = xb + (size_t)src * C_;
            a0 = fmaf(xr[tid], wgt, a0);
            a1 = fmaf(xr[tid + 256], wgt, a1);
            a2 = fmaf(xr[tid + 512], wgt, a2);
        }
        v0 = a0 * inv; v1 = a1 * inv; v2 = a2 * inv;
        rep[(size_t)b * C_ + tid] = v0;
        rep[(size_t)b * C_ + tid + 256] = v1;
        rep[(size_t)b * C_ + tid + 512] = v2;
        ldsRow = 99;
    } else {
        const int jf = t - (NKEEP + 2);
        const int src = 1 + idx[b * NP_ + NKEEP + jf];
#pragma unroll
        for (int j = 0; j < 3; ++j) {
            const int c = tid + j * 256;
            fast[((size_t)b * (NP_ - NKEEP) + jf) * C_ + c] = xb[(size_t)src * C_ + c];
        }
        return;
    }

    float* xsr = xs + ((size_t)b * 100 + ldsRow) * C_;
    xsr[tid] = v0; xsr[tid + 256] = v1; xsr[tid + 512] = v2;

    const float mu = blockReduceSum256(v0 + v1 + v2) * (1.f / C_);
    const float d0 = v0 - mu, d1 = v1 - mu, d2 = v2 - mu;
    const float var = blockReduceSum256(d0 * d0 + d1 * d1 + d2 * d2) * (1.f / C_);
    const float rs = rsqrtf(var + 1e-6f);
    __hip_bfloat16* tr = tb + ((size_t)b * 100 + ldsRow) * C_;
    tr[tid]       = __float2bfloat16(d0 * rs * lng[tid]       + lnb[tid]);
    tr[tid + 256] = __float2bfloat16(d1 * rs * lng[tid + 256] + lnb[tid + 256]);
    tr[tid + 512] = __float2bfloat16(d2 * rs * lng[tid + 512] + lnb[tid + 512]);
}

__global__ __launch_bounds__(256) void scatter_back_kernel(const float* __restrict__ xs,
                                                           const float* __restrict__ fast,
                                                           const float* __restrict__ rep,
                                                           float* __restrict__ x)
{
    const int b = blockIdx.x, t = blockIdx.y, tid = threadIdx.x;
#pragma unroll
    for (int j = 0; j < 3; ++j) {
        const int c = tid + j * 256;
        float v;
        if (t <= NKEEP)
            v = xs[((size_t)b * 100 + t) * C_ + c];
        else
            v = fast[((size_t)b * (NP_ - NKEEP) + (t - NKEEP - 1)) * C_ + c]
                + 0.5f * (xs[((size_t)b * 100 + 99) * C_ + c] - rep[(size_t)b * C_ + c]);
        x[((size_t)b * NTOK + t) * C_ + c] = v;
    }
}

// ---------------- host ----------------
extern "C" void kernel_launch(void* const* d_in, const int* in_sizes, int n_in,
                              void* d_out, int out_size, void* d_ws, size_t ws_size,
                              hipStream_t stream)
{
    (void)in_sizes; (void)n_in; (void)out_size;
    const float* x_img   = (const float*)d_in[0];
    const float* cls_tok = (const float*)d_in[1];
    const float* pos     = (const float*)d_in[2];
    const float* patch_w = (const float*)d_in[3];
    const float* patch_b = (const float*)d_in[4];
    const float* ln1_g   = (const float*)d_in[5];
    const float* ln1_b   = (const float*)d_in[6];
    const float* qk_w    = (const float*)d_in[7];
    const float* qk_b    = (const float*)d_in[8];
    const float* v_w     = (const float*)d_in[9];
    const float* v_b     = (const float*)d_in[10];
    const float* proj_w  = (const float*)d_in[11];
    const float* proj_b  = (const float*)d_in[12];
    const float* ln2_g   = (const float*)d_in[13];
    const float* ln2_b   = (const float*)d_in[14];
    const float* fc1_w   = (const float*)d_in[15];
    const float* fc1_b   = (const float*)d_in[16];
    const float* fc2_w   = (const float*)d_in[17];
    const float* fc2_b   = (const float*)d_in[18];
    const float* norm_g  = (const float*)d_in[19];
    const float* norm_b  = (const float*)d_in[20];
    const float* head_w  = (const float*)d_in[21];
    const float* head_b  = (const float*)d_in[22];

    char* base = (char*)d_ws;
    size_t off = 0;
    auto alloc = [&](size_t bytes) -> void* {
        void* p = base + off; off = (off + bytes + 255) & ~(size_t)255; return p;
    };
    float* X    = (float*)alloc((size_t)MPAD * C_ * 4);
    __hip_bfloat16* Tb   = (__hip_bfloat16*)alloc((size_t)MPAD * C_ * 2);
    __hip_bfloat16* QKVb = (__hip_bfloat16*)alloc((size_t)MPAD * RS_ * 2);
    __hip_bfloat16* Hb   = (__hip_bfloat16*)alloc((size_t)MPAD * 4 * C_ * 2);
    float* XS   = (float*)alloc((size_t)3200 * C_ * 4);
    float* FAST = (float*)alloc((size_t)B_ * (NP_ - NKEEP) * C_ * 4);
    float* REP  = (float*)alloc((size_t)B_ * C_ * 4);
    float* ATTN0= (float*)alloc((size_t)B_ * NH_ * NTOK * 4);
    float* CLS  = (float*)alloc((size_t)B_ * NP_ * 4);
    float* SORT = (float*)alloc((size_t)B_ * NP_ * 4);
    float* SSUM = (float*)alloc((size_t)B_ * 4);
    float* T0   = (float*)alloc((size_t)B_ * C_ * 4);
    int*   IDX  = (int*)alloc((size_t)B_ * NP_ * 4);
    float* BIASQKV = (float*)alloc((size_t)12 * RS_ * 4);
    __hip_bfloat16* WTpatch = (__hip_bfloat16*)alloc((size_t)C_ * C_ * 2);
    __hip_bfloat16* WTqkv   = (__hip_bfloat16*)alloc((size_t)12 * RS_ * C_ * 2);
    __hip_bfloat16* WTproj  = (__hip_bfloat16*)alloc((size_t)12 * C_ * C_ * 2);
    __hip_bfloat16* WTfc1   = (__hip_bfloat16*)alloc((size_t)12 * C_ * 4 * C_ * 2);
    __hip_bfloat16* WTfc2   = (__hip_bfloat16*)alloc((size_t)12 * 4 * C_ * C_ * 2);
    if (off > ws_size) return;

    __hip_bfloat16* Ob    = Hb;          // attn output aliases Hb
    __hip_bfloat16* PATCH = Hb;
    float*          PEMB  = (float*)QKVb;

    const dim3 blk(256);

    // ---- weight transposes (fp32 [K][N] -> bf16 [N][K]) ----
    transpose_bf16_kernel<<<dim3(24, 24, 1), blk, 0, stream>>>(patch_w, WTpatch, C_, C_, (long long)C_ * C_, 0);
    transpose_bf16_kernel<<<dim3(48, 24, 12), blk, 0, stream>>>(qk_w, WTqkv, C_, 2 * C_, (long long)RS_ * C_, 0);
    transpose_bf16_kernel<<<dim3(24, 24, 12), blk, 0, stream>>>(v_w, WTqkv, C_, C_, (long long)RS_ * C_, (long long)2 * C_ * C_);
    transpose_bf16_kernel<<<dim3(24, 24, 12), blk, 0, stream>>>(proj_w, WTproj, C_, C_, (long long)C_ * C_, 0);
    transpose_bf16_kernel<<<dim3(96, 24, 12), blk, 0, stream>>>(fc1_w, WTfc1, C_, 4 * C_, (long long)4 * C_ * C_, 0);
    transpose_bf16_kernel<<<dim3(24, 96, 12), blk, 0, stream>>>(fc2_w, WTfc2, 4 * C_, C_, (long long)4 * C_ * C_, 0);
    concat_bias_kernel<<<(12 * RS_ + 255) / 256, blk, 0, stream>>>(qk_b, v_b, BIASQKV);

    auto runBlock = [&](int i, float* xb, int Nt, bool skipLn1) {
        const int M = B_ * Nt;
        const int mt = (M + 127) >> 7;
        const int mt64 = (M + 63) >> 6;
        const int qtiles = (Nt + 63) >> 6;
        if (!skipLn1)
            ln_kernel<<<(M + 3) / 4, blk, 0, stream>>>(xb, ln1_g + i * C_, ln1_b + i * C_, Tb, nullptr, C_, M);
        gemm_bf16_kernel<0, 0><<<dim3(RS_ / 128, mt), blk, 0, stream>>>(
            Tb, WTqkv + (size_t)i * RS_ * C_, BIASQKV + (size_t)i * RS_, nullptr, nullptr, QKVb, C_, RS_);
        if (Nt == NTOK)
            attn_mfma_kernel<14><<<dim3(B_ * NH_, qtiles), blk, 0, stream>>>(QKVb, Ob, ATTN0, Nt);
        else
            attn_mfma_kernel<8><<<dim3(B_ * NH_, qtiles), blk, 0, stream>>>(QKVb, Ob, ATTN0, Nt);
        gemm_half_kernel<1><<<dim3(6, mt64), blk, 0, stream>>>(
            Ob, WTproj + (size_t)i * C_ * C_, proj_b + (size_t)i * C_, xb, xb, C_, C_);
        ln_kernel<<<(M + 3) / 4, blk, 0, stream>>>(xb, ln2_g + i * C_, ln2_b + i * C_, Tb, nullptr, C_, M);
        gemm_bf16_kernel<1, 0><<<dim3(24, mt), blk, 0, stream>>>(
            Tb, WTfc1 + (size_t)i * C_ * 4 * C_, fc1_b + (size_t)i * 4 * C_, nullptr, nullptr, Hb, C_, 4 * C_);
        gemm_half_kernel<1><<<dim3(6, mt64), blk, 0, stream>>>(
            Hb, WTfc2 + (size_t)i * 4 * C_ * C_, fc2_b + (size_t)i * C_, xb, xb, 4 * C_, C_);
    };

    // ---- patch embedding ----
    patchify_kernel<<<B_ * NP_, blk, 0, stream>>>(x_img, PATCH);
    gemm_half_kernel<2><<<dim3(6, 98), blk, 0, stream>>>(
        PATCH, WTpatch, patch_b, nullptr, PEMB, C_, C_);
    assemble_x_kernel<<<dim3(B_, NTOK), blk, 0, stream>>>(PEMB, cls_tok, pos, X);

    // ---- 12 transformer blocks ----
    for (int i = 0; i < 12; ++i) {
        if (i < 4) {
            runBlock(i, X, NTOK, false);
            row_cls_ema_kernel<<<B_, blk, 0, stream>>>(ATTN0, CLS, i == 0 ? 1 : 0);
        } else {
            rank_kernel<<<B_, blk, 0, stream>>>(CLS, IDX, SORT, SSUM);
            build_xs_kernel<<<dim3(B_, 198), blk, 0, stream>>>(
                X, IDX, SORT, SSUM, XS, FAST, REP, ln1_g + i * C_, ln1_b + i * C_, Tb);
            runBlock(i, XS, 100, true);
            scatter_back_kernel<<<dim3(B_, NTOK), blk, 0, stream>>>(XS, FAST, REP, X);
            row_cls_prune_kernel<<<B_, blk, 0, stream>>>(ATTN0, SORT, CLS);
        }
    }

    // ---- final LN (token 0 only) + head (fp32 exact) ----
    ln_kernel<<<8, blk, 0, stream>>>(X, norm_g, norm_b, nullptr, T0, (long long)NTOK * C_, B_);
    head_kernel<<<dim3(4, B_), blk, 0, stream>>>(T0, head_w, head_b, (float*)d_out);
}